// Round 11
// baseline (171.992 us; speedup 1.0000x reference)
//
#include <hip/hip_runtime.h>
#include <hip/hip_bf16.h>
#include <stdint.h>

#define DM 1024
#define NS 16
#define LSEQ 4096
#define NB 4
#define MTOT (NB*LSEQ)   // 16384
#define NC 128           // scan chunks per sequence
#define LC 32            // LSEQ/NC

typedef __attribute__((ext_vector_type(8))) short bf16x8;
typedef __attribute__((ext_vector_type(4))) float f32x4;

__device__ __forceinline__ unsigned short f2bf(float f) {
    unsigned int u = __float_as_uint(f);
    unsigned int r = (u + 0x7FFFu + ((u >> 16) & 1u)) >> 16;
    return (unsigned short)r;
}

__device__ __forceinline__ float bf2f(unsigned short u) {
    return __uint_as_float(((unsigned int)u) << 16);
}

// fast softplus: v_exp_f32 + v_log_f32, no log1pf libcall
__device__ __forceinline__ float softplus_f(float v) {
    return v > 15.f ? v : __logf(1.f + __expf(v));
}

__device__ __forceinline__ void gload_lds16(const void* g, void* l) {
    __builtin_amdgcn_global_load_lds(
        (const __attribute__((address_space(1))) unsigned int*)g,
        (__attribute__((address_space(3))) unsigned int*)l, 16, 0, 0);
}

__device__ __forceinline__ bf16x8 cvt8(const float* p) {
    float4 v0 = *(const float4*)p;
    float4 v1 = *(const float4*)(p + 4);
    bf16x8 r;
    r[0] = (short)f2bf(v0.x); r[1] = (short)f2bf(v0.y);
    r[2] = (short)f2bf(v0.z); r[3] = (short)f2bf(v0.w);
    r[4] = (short)f2bf(v1.x); r[5] = (short)f2bf(v1.y);
    r[6] = (short)f2bf(v1.z); r[7] = (short)f2bf(v1.w);
    return r;
}

// ---------------- pre-pass: streaming conversions + co-scheduled Bx MFMA ----------------
// blocks [0,16384):     x -> bf16 (one row each)
// blocks [16384,17408): W -> bf16
// blocks [17408,17424): zero delta_raw
// blocks [17424,17680): Bx = x@B^T via MFMA, reading f32 x/B DIRECTLY with in-register
//                       bf16 convert (no dependence on sibling blocks' output -> no race;
//                       G16-safe under any dispatch order). Compute-light, rides the
//                       HBM-bound window; dispatched last so x reads are L3-hot.
__global__ __launch_bounds__(256) void pre_kernel(
    const float* __restrict__ x, const float* __restrict__ W,
    const float* __restrict__ B, ushort4* __restrict__ xb4,
    ushort4* __restrict__ wb4, float* __restrict__ delta_raw,
    float* __restrict__ Bx)
{
    int bid = blockIdx.x, t = threadIdx.x;
    if (bid < 16384) {
        size_t i = (size_t)bid * 256 + t;
        float4 v = ((const float4*)x)[i];
        ushort4 o; o.x = f2bf(v.x); o.y = f2bf(v.y); o.z = f2bf(v.z); o.w = f2bf(v.w);
        xb4[i] = o;
    } else if (bid < 17408) {
        int i = (bid - 16384) * 256 + t;
        float4 v = ((const float4*)W)[i];
        ushort4 o; o.x = f2bf(v.x); o.y = f2bf(v.y); o.z = f2bf(v.z); o.w = f2bf(v.w);
        wb4[i] = o;
    } else if (bid < 17424) {
        int i = (bid - 17408) * 256 + t;
        ((float4*)delta_raw)[i] = (float4){0.f, 0.f, 0.f, 0.f};
    } else {
        int bb = bid - 17424;                 // 0..255
        int lane = t & 63, w4 = t >> 6;
        int r0 = (bb * 4 + w4) * 16;          // wave covers x-rows r0..r0+15
        int lm = lane & 15, lk = lane >> 4;
        const float* pa = x + (size_t)(r0 + lm) * DM + lk * 8;
        const float* pb = B + (size_t)lm * DM + lk * 8;
        f32x4 acc = (f32x4){0.f, 0.f, 0.f, 0.f};
        #pragma unroll 4
        for (int k0 = 0; k0 < DM; k0 += 32) {
            bf16x8 a = cvt8(pa + k0);
            bf16x8 b = cvt8(pb + k0);
            acc = __builtin_amdgcn_mfma_f32_16x16x32_bf16(a, b, acc, 0, 0, 0);
        }
        #pragma unroll
        for (int r = 0; r < 4; ++r)
            Bx[(size_t)(r0 + lk * 4 + r) * NS + lm] = acc[r];   // D: col=lm, row=lk*4+r
    }
}

// ---------------- delta GEMM: S = x @ W^T, softplus+sum over e -> atomicAdd ----------------
// 256x256 tile, BK=64, 8 waves (2M x 4N), 16x16x32 bf16 MFMA, 4-sub-phase
// counted-vmcnt schedule. ROUND-9 PROVEN (42.4 us, 810 TF) — byte-identical revert;
// no extra VMEM ops inside the counted loop (round-10 lesson).
__global__ __launch_bounds__(512) void gemm_delta(
    const unsigned short* __restrict__ xb, const unsigned short* __restrict__ wb,
    const float* __restrict__ b_delta, float* __restrict__ delta_raw)
{
    __shared__ char lds[131072];
    int bid = blockIdx.x;
    int swz = (bid & 7) * 32 + (bid >> 3);    // XCD-aware, bijective (256 % 8 == 0)
    int mb = swz >> 2, nb = swz & 3;
    int row0 = mb * 256, e0 = nb * 256;
    int tid = threadIdx.x;
    int lane = tid & 63, w = tid >> 6;        // 8 waves
    int wr = w >> 2, wc = w & 3;              // 2M x 4N
    int lm = lane & 15, lk = lane >> 4;

    // pre-swizzled source column (elements): chunk_log = chunk_phys ^ (row&7)
    int colsw = ((lane & 7) * 8) ^ ((lane >> 3) << 3);
    int rsub = lane >> 3;                     // row within 8-row region

    const unsigned short* pA[4];
    const unsigned short* pB[4];
    #pragma unroll
    for (int j = 0; j < 4; ++j) {
        int region = w * 4 + j;               // 0..31
        int r0 = region * 8 + rsub;           // 0..255
        pA[j] = xb + (size_t)(row0 + r0) * DM + colsw;
        pB[j] = wb + (size_t)(e0  + r0) * DM + colsw;
    }

    // compute-read offsets: FULL XOR off(kk) = (kk*64 + lk*16) ^ ((lm&7)<<4)
    int sterm = (lm & 7) << 4;
    int off0 = (lk * 16) ^ sterm;
    int off1 = (64 + lk * 16) ^ sterm;
    int aBase = (wr * 128 + lm) * 128;             // + m*2048 + off{0,1}
    int bBase = 32768 + (wc * 64 + lm) * 128;      // + n*2048 + off{0,1}

    f32x4 acc[8][4];
    #pragma unroll
    for (int m = 0; m < 8; ++m)
        #pragma unroll
        for (int n = 0; n < 4; ++n)
            acc[m][n] = (f32x4){0.f, 0.f, 0.f, 0.f};

    bf16x8 bq[4][2];   // B fragments, loaded once per K-tile (phase 0), static idx

#define STAGE_Q(BUF, Q, KOFF) do { \
    gload_lds16(pA[Q] + (KOFF), lds + (BUF) + ((w * 4 + (Q)) * 1024)); \
    gload_lds16(pB[Q] + (KOFF), lds + (BUF) + 32768 + ((w * 4 + (Q)) * 1024)); \
} while (0)

#define PHASE(CUR, NXT, KOFF, STG, Q) do { \
    if (STG) STAGE_Q(NXT, Q, KOFF); \
    if ((Q) == 0) { \
        if (STG) asm volatile("s_waitcnt vmcnt(2)\n\ts_barrier" ::: "memory"); \
        else     asm volatile("s_waitcnt vmcnt(0)\n\ts_barrier" ::: "memory"); \
        _Pragma("unroll") \
        for (int n = 0; n < 4; ++n) { \
            bq[n][0] = *(const bf16x8*)(lds + (CUR) + bBase + n * 2048 + off0); \
            bq[n][1] = *(const bf16x8*)(lds + (CUR) + bBase + n * 2048 + off1); \
        } \
    } \
    bf16x8 a0 = *(const bf16x8*)(lds + (CUR) + aBase + (2*(Q)) * 2048 + off0); \
    bf16x8 a1 = *(const bf16x8*)(lds + (CUR) + aBase + (2*(Q)) * 2048 + off1); \
    bf16x8 a2 = *(const bf16x8*)(lds + (CUR) + aBase + (2*(Q)+1) * 2048 + off0); \
    bf16x8 a3 = *(const bf16x8*)(lds + (CUR) + aBase + (2*(Q)+1) * 2048 + off1); \
    asm volatile("s_barrier" ::: "memory"); \
    __builtin_amdgcn_s_setprio(1); \
    _Pragma("unroll") \
    for (int n = 0; n < 4; ++n) { \
        acc[2*(Q)][n]   = __builtin_amdgcn_mfma_f32_16x16x32_bf16(a0, bq[n][0], acc[2*(Q)][n], 0, 0, 0); \
        acc[2*(Q)][n]   = __builtin_amdgcn_mfma_f32_16x16x32_bf16(a1, bq[n][1], acc[2*(Q)][n], 0, 0, 0); \
        acc[2*(Q)+1][n] = __builtin_amdgcn_mfma_f32_16x16x32_bf16(a2, bq[n][0], acc[2*(Q)+1][n], 0, 0, 0); \
        acc[2*(Q)+1][n] = __builtin_amdgcn_mfma_f32_16x16x32_bf16(a3, bq[n][1], acc[2*(Q)+1][n], 0, 0, 0); \
    } \
    __builtin_amdgcn_s_setprio(0); \
    asm volatile("s_barrier" ::: "memory"); \
} while (0)

#define KTILE(CUR, NXT, KOFF, STG) do { \
    PHASE(CUR, NXT, KOFF, STG, 0); \
    PHASE(CUR, NXT, KOFF, STG, 1); \
    PHASE(CUR, NXT, KOFF, STG, 2); \
    PHASE(CUR, NXT, KOFF, STG, 3); \
} while (0)

    // prologue: stage ALL of tile 0 into buf0 (8 loads outstanding)
    STAGE_Q(0, 0, 0); STAGE_Q(0, 1, 0); STAGE_Q(0, 2, 0); STAGE_Q(0, 3, 0);
    int koff = 64;
    #pragma unroll 1
    for (int it = 0; it < 7; ++it) {
        KTILE(0,     65536, koff,      true);   // even tile, stages odd tile
        KTILE(65536, 0,     koff + 64, true);   // odd tile,  stages even tile
        koff += 128;
    }
    KTILE(0, 65536, 960, true);    // tile 14, stages tile 15
    KTILE(65536, 0, 0, false);     // tile 15, no staging (vmcnt(0) in its phase 0)

#undef KTILE
#undef PHASE
#undef STAGE_Q

    // epilogue: softplus(S + b_delta), reduce over this wave's 64 e-cols, atomicAdd per row
    float bd[4];
    #pragma unroll
    for (int n = 0; n < 4; ++n) bd[n] = b_delta[e0 + wc * 64 + n * 16 + lm];
    #pragma unroll
    for (int m = 0; m < 8; ++m) {
        #pragma unroll
        for (int r = 0; r < 4; ++r) {
            float s = 0.f;
            #pragma unroll
            for (int n = 0; n < 4; ++n) s += softplus_f(acc[m][n][r] + bd[n]);
            s += __shfl_xor(s, 1, 16);
            s += __shfl_xor(s, 2, 16);
            s += __shfl_xor(s, 4, 16);
            s += __shfl_xor(s, 8, 16);
            if (lm == 0) {
                int row = row0 + wr * 128 + m * 16 + lk * 4 + r;  // C/D: row=(lane>>4)*4+reg
                atomicAdd(&delta_raw[row], s);
            }
        }
    }
}

// ---------------- scan pass 1: per-chunk (P = prod dA, h_local) ----------------
__global__ __launch_bounds__(64) void scan_pass1(
    const float* __restrict__ delta_raw, const float* __restrict__ Bx,
    const float* __restrict__ A_log, float* __restrict__ cP, float* __restrict__ cH)
{
    __shared__ float dl[LC];
    __shared__ float bxl[LC * NS];
    int bid = blockIdx.x;
    int b = bid >> 7, c = bid & 127;
    int l0 = c * LC;
    int t = threadIdx.x;
    size_t base = (size_t)b * LSEQ + l0;
    if (t < LC) dl[t] = delta_raw[base + t] * (1.f / 1024.f);
    const float4* src = (const float4*)(Bx + base * NS);
    float4* dst = (float4*)bxl;
    dst[t] = src[t];
    dst[t + 64] = src[t + 64];
    __syncthreads();
    if (t < NS) {
        float a = -__expf(A_log[t]);
        float P = 1.f, h = 0.f;
        #pragma unroll
        for (int s = 0; s < LC; ++s) {
            float dlt = dl[s];
            float dA = __expf(dlt * a);
            h = dA * h + dlt * bxl[s * NS + t];
            P *= dA;
        }
        int idx = (b * NC + c) * NS + t;
        cP[idx] = P; cH[idx] = h;
    }
}

// ---------------- pass 3: per-chunk prefix combine + hs regen + fused y ----------------
__global__ __launch_bounds__(256) void y_kernel(
    const unsigned short* __restrict__ xb, const float* __restrict__ delta_raw,
    const float* __restrict__ Bx, const float* __restrict__ A_log,
    const float* __restrict__ cP, const float* __restrict__ cH,
    const float* __restrict__ C, const float* __restrict__ Dv, float* __restrict__ y)
{
    __shared__ float dl[LC];
    __shared__ float bxl[LC * NS];
    __shared__ float hsl[LC * NS];
    __shared__ float pbuf[NC * NS];
    __shared__ float hbuf[NC * NS];
    int bid = blockIdx.x;
    int b = bid >> 7, c = bid & 127;
    int l0 = c * LC;
    int t = threadIdx.x;
    size_t base = (size_t)b * LSEQ + l0;
    if (t < LC) dl[t] = delta_raw[base + t] * (1.f / 1024.f);
    if (t < 128) ((float4*)bxl)[t] = ((const float4*)(Bx + base * NS))[t];
    {
        const float4* p4 = (const float4*)(cP + (size_t)b * NC * NS);
        const float4* h4 = (const float4*)(cH + (size_t)b * NC * NS);
        ((float4*)pbuf)[t] = p4[t];         ((float4*)pbuf)[t + 256] = p4[t + 256];
        ((float4*)hbuf)[t] = h4[t];         ((float4*)hbuf)[t + 256] = h4[t + 256];
    }
    __syncthreads();
    if (t < NS) {
        float h = 0.f;
        for (int cc = 0; cc < c; ++cc) {
            int idx = cc * NS + t;
            h = pbuf[idx] * h + hbuf[idx];
        }
        float a = -__expf(A_log[t]);
        #pragma unroll
        for (int s = 0; s < LC; ++s) {
            float dlt = dl[s];
            float dA = __expf(dlt * a);
            h = dA * h + dlt * bxl[s * NS + t];
            hsl[s * NS + t] = h;
        }
    }
    __syncthreads();

    int d0 = t * 4;
    float cr[4][NS];
    #pragma unroll
    for (int dd = 0; dd < 4; ++dd)
        #pragma unroll
        for (int nn = 0; nn < 4; ++nn) {
            float4 c4 = ((const float4*)C)[((d0 + dd) * NS + nn * 4) >> 2];
            cr[dd][nn * 4 + 0] = c4.x; cr[dd][nn * 4 + 1] = c4.y;
            cr[dd][nn * 4 + 2] = c4.z; cr[dd][nn * 4 + 3] = c4.w;
        }
    float4 dv = ((const float4*)Dv)[t];
    const ushort4* xr = (const ushort4*)(xb + base * DM) + t;
    float4* yr = (float4*)(y + base * DM) + t;
    for (int s = 0; s < LC; ++s) {
        float hv[NS];
        #pragma unroll
        for (int n = 0; n < NS; ++n) hv[n] = hsl[s * NS + n];
        ushort4 xv4 = xr[s * 256];
        float4 o;
        o.x = dv.x * bf2f(xv4.x); o.y = dv.y * bf2f(xv4.y);
        o.z = dv.z * bf2f(xv4.z); o.w = dv.w * bf2f(xv4.w);
        #pragma unroll
        for (int n = 0; n < NS; ++n) {
            o.x += hv[n] * cr[0][n];
            o.y += hv[n] * cr[1][n];
            o.z += hv[n] * cr[2][n];
            o.w += hv[n] * cr[3][n];
        }
        yr[s * 256] = o;
    }
}

extern "C" void kernel_launch(void* const* d_in, const int* in_sizes, int n_in,
                              void* d_out, int out_size, void* d_ws, size_t ws_size,
                              hipStream_t stream)
{
    const float* x     = (const float*)d_in[0];
    const float* A_log = (const float*)d_in[1];
    const float* B     = (const float*)d_in[2];
    const float* C     = (const float*)d_in[3];
    const float* Dv    = (const float*)d_in[4];
    const float* Wd    = (const float*)d_in[5];
    const float* bd    = (const float*)d_in[6];
    float* y = (float*)d_out;

    char* ws = (char*)d_ws;
    unsigned short* xb = (unsigned short*)ws;                  // 33,554,432 B
    unsigned short* wb = (unsigned short*)(ws + 33554432);     //  2,097,152 B
    float* delta_raw   = (float*)(ws + 35651584);              //     65,536 B
    float* Bx          = (float*)(ws + 35717120);              //  1,048,576 B
    float* cP          = (float*)(ws + 36765696);              //     32,768 B
    float* cH          = (float*)(ws + 36798464);              //     32,768 B

    pre_kernel<<<17680, 256, 0, stream>>>(x, Wd, B, (ushort4*)xb, (ushort4*)wb,
                                          delta_raw, Bx);
    gemm_delta<<<256, 512, 0, stream>>>(xb, wb, bd, delta_raw);
    scan_pass1<<<NB * NC, 64, 0, stream>>>(delta_raw, Bx, A_log, cP, cH);
    y_kernel<<<NB * NC, 256, 0, stream>>>(xb, delta_raw, Bx, A_log, cP, cH, C, Dv, y);
}

// Round 12
// 92.209 us; speedup vs baseline: 1.8652x; 1.8652x over previous
//
#include <hip/hip_runtime.h>
#include <hip/hip_bf16.h>
#include <stdint.h>

#define DM 1024
#define NS 16
#define LSEQ 4096
#define NB 4
#define MTOT (NB*LSEQ)   // 16384
#define NC 128           // scan chunks per sequence
#define LC 32            // LSEQ/NC

typedef __attribute__((ext_vector_type(8))) short bf16x8;
typedef __attribute__((ext_vector_type(4))) float f32x4;

__device__ __forceinline__ unsigned short f2bf(float f) {
    unsigned int u = __float_as_uint(f);
    unsigned int r = (u + 0x7FFFu + ((u >> 16) & 1u)) >> 16;
    return (unsigned short)r;
}

__device__ __forceinline__ float bf2f(unsigned short u) {
    return __uint_as_float(((unsigned int)u) << 16);
}

// fast softplus: v_exp_f32 + v_log_f32, no log1pf libcall
__device__ __forceinline__ float softplus_f(float v) {
    return v > 15.f ? v : __logf(1.f + __expf(v));
}

__device__ __forceinline__ void gload_lds16(const void* g, void* l) {
    __builtin_amdgcn_global_load_lds(
        (const __attribute__((address_space(1))) unsigned int*)g,
        (__attribute__((address_space(3))) unsigned int*)l, 16, 0, 0);
}

// ---------------- pre-pass: pure streaming conversions (ROUND-9 PROVEN, 17.5 us) --------
// blocks [0,16384):     x -> bf16 (one row each)
// blocks [16384,17408): W -> bf16
// blocks [17408,17424): B -> bf16
// blocks [17424,17440): zero delta_raw
__global__ __launch_bounds__(256) void pre_kernel(
    const float4* __restrict__ x4, const float4* __restrict__ W4,
    const float4* __restrict__ B4, ushort4* __restrict__ xb4,
    ushort4* __restrict__ wb4, ushort4* __restrict__ bbf4,
    float* __restrict__ delta_raw)
{
    int bid = blockIdx.x, t = threadIdx.x;
    if (bid < 16384) {
        size_t i = (size_t)bid * 256 + t;
        float4 v = x4[i];
        ushort4 o; o.x = f2bf(v.x); o.y = f2bf(v.y); o.z = f2bf(v.z); o.w = f2bf(v.w);
        xb4[i] = o;
    } else if (bid < 17408) {
        int i = (bid - 16384) * 256 + t;
        float4 v = W4[i];
        ushort4 o; o.x = f2bf(v.x); o.y = f2bf(v.y); o.z = f2bf(v.z); o.w = f2bf(v.w);
        wb4[i] = o;
    } else if (bid < 17424) {
        int i = (bid - 17408) * 256 + t;
        float4 v = B4[i];
        ushort4 o; o.x = f2bf(v.x); o.y = f2bf(v.y); o.z = f2bf(v.z); o.w = f2bf(v.w);
        bbf4[i] = o;
    } else {
        int i = (bid - 17424) * 256 + t;
        ((float4*)delta_raw)[i] = (float4){0.f, 0.f, 0.f, 0.f};
    }
}

// ---------------- delta GEMM: S = x @ W^T, softplus+sum over e -> atomicAdd ----------------
// 256x256 tile, BK=64, 8 waves (2M x 4N), 16x16x32 bf16 MFMA, 4-sub-phase
// counted-vmcnt schedule. ROUND-9 PROVEN (42.4 us, 810 TF) — byte-identical;
// no extra VMEM ops inside the counted loop (round-10 lesson).
__global__ __launch_bounds__(512) void gemm_delta(
    const unsigned short* __restrict__ xb, const unsigned short* __restrict__ wb,
    const float* __restrict__ b_delta, float* __restrict__ delta_raw)
{
    __shared__ char lds[131072];
    int bid = blockIdx.x;
    int swz = (bid & 7) * 32 + (bid >> 3);    // XCD-aware, bijective (256 % 8 == 0)
    int mb = swz >> 2, nb = swz & 3;
    int row0 = mb * 256, e0 = nb * 256;
    int tid = threadIdx.x;
    int lane = tid & 63, w = tid >> 6;        // 8 waves
    int wr = w >> 2, wc = w & 3;              // 2M x 4N
    int lm = lane & 15, lk = lane >> 4;

    // pre-swizzled source column (elements): chunk_log = chunk_phys ^ (row&7)
    int colsw = ((lane & 7) * 8) ^ ((lane >> 3) << 3);
    int rsub = lane >> 3;                     // row within 8-row region

    const unsigned short* pA[4];
    const unsigned short* pB[4];
    #pragma unroll
    for (int j = 0; j < 4; ++j) {
        int region = w * 4 + j;               // 0..31
        int r0 = region * 8 + rsub;           // 0..255
        pA[j] = xb + (size_t)(row0 + r0) * DM + colsw;
        pB[j] = wb + (size_t)(e0  + r0) * DM + colsw;
    }

    // compute-read offsets: FULL XOR off(kk) = (kk*64 + lk*16) ^ ((lm&7)<<4)
    int sterm = (lm & 7) << 4;
    int off0 = (lk * 16) ^ sterm;
    int off1 = (64 + lk * 16) ^ sterm;
    int aBase = (wr * 128 + lm) * 128;             // + m*2048 + off{0,1}
    int bBase = 32768 + (wc * 64 + lm) * 128;      // + n*2048 + off{0,1}

    f32x4 acc[8][4];
    #pragma unroll
    for (int m = 0; m < 8; ++m)
        #pragma unroll
        for (int n = 0; n < 4; ++n)
            acc[m][n] = (f32x4){0.f, 0.f, 0.f, 0.f};

    bf16x8 bq[4][2];   // B fragments, loaded once per K-tile (phase 0), static idx

#define STAGE_Q(BUF, Q, KOFF) do { \
    gload_lds16(pA[Q] + (KOFF), lds + (BUF) + ((w * 4 + (Q)) * 1024)); \
    gload_lds16(pB[Q] + (KOFF), lds + (BUF) + 32768 + ((w * 4 + (Q)) * 1024)); \
} while (0)

#define PHASE(CUR, NXT, KOFF, STG, Q) do { \
    if (STG) STAGE_Q(NXT, Q, KOFF); \
    if ((Q) == 0) { \
        if (STG) asm volatile("s_waitcnt vmcnt(2)\n\ts_barrier" ::: "memory"); \
        else     asm volatile("s_waitcnt vmcnt(0)\n\ts_barrier" ::: "memory"); \
        _Pragma("unroll") \
        for (int n = 0; n < 4; ++n) { \
            bq[n][0] = *(const bf16x8*)(lds + (CUR) + bBase + n * 2048 + off0); \
            bq[n][1] = *(const bf16x8*)(lds + (CUR) + bBase + n * 2048 + off1); \
        } \
    } \
    bf16x8 a0 = *(const bf16x8*)(lds + (CUR) + aBase + (2*(Q)) * 2048 + off0); \
    bf16x8 a1 = *(const bf16x8*)(lds + (CUR) + aBase + (2*(Q)) * 2048 + off1); \
    bf16x8 a2 = *(const bf16x8*)(lds + (CUR) + aBase + (2*(Q)+1) * 2048 + off0); \
    bf16x8 a3 = *(const bf16x8*)(lds + (CUR) + aBase + (2*(Q)+1) * 2048 + off1); \
    asm volatile("s_barrier" ::: "memory"); \
    __builtin_amdgcn_s_setprio(1); \
    _Pragma("unroll") \
    for (int n = 0; n < 4; ++n) { \
        acc[2*(Q)][n]   = __builtin_amdgcn_mfma_f32_16x16x32_bf16(a0, bq[n][0], acc[2*(Q)][n], 0, 0, 0); \
        acc[2*(Q)][n]   = __builtin_amdgcn_mfma_f32_16x16x32_bf16(a1, bq[n][1], acc[2*(Q)][n], 0, 0, 0); \
        acc[2*(Q)+1][n] = __builtin_amdgcn_mfma_f32_16x16x32_bf16(a2, bq[n][0], acc[2*(Q)+1][n], 0, 0, 0); \
        acc[2*(Q)+1][n] = __builtin_amdgcn_mfma_f32_16x16x32_bf16(a3, bq[n][1], acc[2*(Q)+1][n], 0, 0, 0); \
    } \
    __builtin_amdgcn_s_setprio(0); \
    asm volatile("s_barrier" ::: "memory"); \
} while (0)

#define KTILE(CUR, NXT, KOFF, STG) do { \
    PHASE(CUR, NXT, KOFF, STG, 0); \
    PHASE(CUR, NXT, KOFF, STG, 1); \
    PHASE(CUR, NXT, KOFF, STG, 2); \
    PHASE(CUR, NXT, KOFF, STG, 3); \
} while (0)

    // prologue: stage ALL of tile 0 into buf0 (8 loads outstanding)
    STAGE_Q(0, 0, 0); STAGE_Q(0, 1, 0); STAGE_Q(0, 2, 0); STAGE_Q(0, 3, 0);
    int koff = 64;
    #pragma unroll 1
    for (int it = 0; it < 7; ++it) {
        KTILE(0,     65536, koff,      true);   // even tile, stages odd tile
        KTILE(65536, 0,     koff + 64, true);   // odd tile,  stages even tile
        koff += 128;
    }
    KTILE(0, 65536, 960, true);    // tile 14, stages tile 15
    KTILE(65536, 0, 0, false);     // tile 15, no staging (vmcnt(0) in its phase 0)

#undef KTILE
#undef PHASE
#undef STAGE_Q

    // epilogue: softplus(S + b_delta), reduce over this wave's 64 e-cols, atomicAdd per row
    float bd[4];
    #pragma unroll
    for (int n = 0; n < 4; ++n) bd[n] = b_delta[e0 + wc * 64 + n * 16 + lm];
    #pragma unroll
    for (int m = 0; m < 8; ++m) {
        #pragma unroll
        for (int r = 0; r < 4; ++r) {
            float s = 0.f;
            #pragma unroll
            for (int n = 0; n < 4; ++n) s += softplus_f(acc[m][n][r] + bd[n]);
            s += __shfl_xor(s, 1, 16);
            s += __shfl_xor(s, 2, 16);
            s += __shfl_xor(s, 4, 16);
            s += __shfl_xor(s, 8, 16);
            if (lm == 0) {
                int row = row0 + wr * 128 + m * 16 + lk * 4 + r;  // C/D: row=(lane>>4)*4+reg
                atomicAdd(&delta_raw[row], s);
            }
        }
    }
}

// ---------------- scan pass 1 + fused Bx MFMA ----------------
// 512 blocks (b,c), 128 threads = 2 waves. Each wave computes Bx = x@B^T for its
// chunk's 16 rows (byte-identical bx_mfma pattern, L3-hot xb/bbf), deposits the
// fragments into LDS + global Bx (for y_kernel); then the 16-lane serial scan
// consumes LDS. Uniform register profile across all waves (round-11 lesson).
__global__ __launch_bounds__(128) void scan_bx(
    const unsigned short* __restrict__ xb, const unsigned short* __restrict__ bbf,
    const float* __restrict__ delta_raw, const float* __restrict__ A_log,
    float* __restrict__ Bx, float* __restrict__ cP, float* __restrict__ cH)
{
    __shared__ float dl[LC];
    __shared__ float bxl[LC * NS];
    int bid = blockIdx.x;
    int b = bid >> 7, c = bid & 127;
    int t = threadIdx.x;
    int lane = t & 63, w4 = t >> 6;       // 2 waves
    size_t base = (size_t)b * LSEQ + c * LC;
    if (t < LC) dl[t] = delta_raw[base + t] * (1.f / 1024.f);

    // Bx via MFMA: wave w4 covers rows base + w4*16 .. +15
    int lm = lane & 15, lk = lane >> 4;
    const unsigned short* pa = xb + (base + w4 * 16 + lm) * DM + lk * 8;
    const unsigned short* pb = bbf + (size_t)lm * DM + lk * 8;
    f32x4 acc = (f32x4){0.f, 0.f, 0.f, 0.f};
    #pragma unroll 4
    for (int k0 = 0; k0 < DM; k0 += 32) {
        bf16x8 a  = *(const bf16x8*)(pa + k0);
        bf16x8 bb = *(const bf16x8*)(pb + k0);
        acc = __builtin_amdgcn_mfma_f32_16x16x32_bf16(a, bb, acc, 0, 0, 0);
    }
    #pragma unroll
    for (int r = 0; r < 4; ++r) {
        int rl = w4 * 16 + lk * 4 + r;    // local row 0..31; D: col=lm, row=lk*4+r
        bxl[rl * NS + lm] = acc[r];
        Bx[(base + rl) * NS + lm] = acc[r];
    }
    __syncthreads();

    if (t < NS) {
        float a = -__expf(A_log[t]);
        float P = 1.f, h = 0.f;
        #pragma unroll
        for (int s = 0; s < LC; ++s) {
            float dlt = dl[s];
            float dA = __expf(dlt * a);
            h = dA * h + dlt * bxl[s * NS + t];
            P *= dA;
        }
        int idx = (b * NC + c) * NS + t;
        cP[idx] = P; cH[idx] = h;
    }
}

// ---------------- pass 3: per-chunk prefix combine + hs regen + fused y ----------------
__global__ __launch_bounds__(256) void y_kernel(
    const unsigned short* __restrict__ xb, const float* __restrict__ delta_raw,
    const float* __restrict__ Bx, const float* __restrict__ A_log,
    const float* __restrict__ cP, const float* __restrict__ cH,
    const float* __restrict__ C, const float* __restrict__ Dv, float* __restrict__ y)
{
    __shared__ float dl[LC];
    __shared__ float bxl[LC * NS];
    __shared__ float hsl[LC * NS];
    __shared__ float pbuf[NC * NS];
    __shared__ float hbuf[NC * NS];
    int bid = blockIdx.x;
    int b = bid >> 7, c = bid & 127;
    int l0 = c * LC;
    int t = threadIdx.x;
    size_t base = (size_t)b * LSEQ + l0;
    if (t < LC) dl[t] = delta_raw[base + t] * (1.f / 1024.f);
    if (t < 128) ((float4*)bxl)[t] = ((const float4*)(Bx + base * NS))[t];
    {
        const float4* p4 = (const float4*)(cP + (size_t)b * NC * NS);
        const float4* h4 = (const float4*)(cH + (size_t)b * NC * NS);
        ((float4*)pbuf)[t] = p4[t];         ((float4*)pbuf)[t + 256] = p4[t + 256];
        ((float4*)hbuf)[t] = h4[t];         ((float4*)hbuf)[t + 256] = h4[t + 256];
    }
    __syncthreads();
    if (t < NS) {
        float h = 0.f;
        for (int cc = 0; cc < c; ++cc) {
            int idx = cc * NS + t;
            h = pbuf[idx] * h + hbuf[idx];
        }
        float a = -__expf(A_log[t]);
        #pragma unroll
        for (int s = 0; s < LC; ++s) {
            float dlt = dl[s];
            float dA = __expf(dlt * a);
            h = dA * h + dlt * bxl[s * NS + t];
            hsl[s * NS + t] = h;
        }
    }
    __syncthreads();

    int d0 = t * 4;
    float cr[4][NS];
    #pragma unroll
    for (int dd = 0; dd < 4; ++dd)
        #pragma unroll
        for (int nn = 0; nn < 4; ++nn) {
            float4 c4 = ((const float4*)C)[((d0 + dd) * NS + nn * 4) >> 2];
            cr[dd][nn * 4 + 0] = c4.x; cr[dd][nn * 4 + 1] = c4.y;
            cr[dd][nn * 4 + 2] = c4.z; cr[dd][nn * 4 + 3] = c4.w;
        }
    float4 dv = ((const float4*)Dv)[t];
    const ushort4* xr = (const ushort4*)(xb + base * DM) + t;
    float4* yr = (float4*)(y + base * DM) + t;
    for (int s = 0; s < LC; ++s) {
        float hv[NS];
        #pragma unroll
        for (int n = 0; n < NS; ++n) hv[n] = hsl[s * NS + n];
        ushort4 xv4 = xr[s * 256];
        float4 o;
        o.x = dv.x * bf2f(xv4.x); o.y = dv.y * bf2f(xv4.y);
        o.z = dv.z * bf2f(xv4.z); o.w = dv.w * bf2f(xv4.w);
        #pragma unroll
        for (int n = 0; n < NS; ++n) {
            o.x += hv[n] * cr[0][n];
            o.y += hv[n] * cr[1][n];
            o.z += hv[n] * cr[2][n];
            o.w += hv[n] * cr[3][n];
        }
        yr[s * 256] = o;
    }
}

extern "C" void kernel_launch(void* const* d_in, const int* in_sizes, int n_in,
                              void* d_out, int out_size, void* d_ws, size_t ws_size,
                              hipStream_t stream)
{
    const float* x     = (const float*)d_in[0];
    const float* A_log = (const float*)d_in[1];
    const float* B     = (const float*)d_in[2];
    const float* C     = (const float*)d_in[3];
    const float* Dv    = (const float*)d_in[4];
    const float* Wd    = (const float*)d_in[5];
    const float* bd    = (const float*)d_in[6];
    float* y = (float*)d_out;

    char* ws = (char*)d_ws;
    unsigned short* xb = (unsigned short*)ws;                  // 33,554,432 B
    unsigned short* wb = (unsigned short*)(ws + 33554432);     //  2,097,152 B
    float* delta_raw   = (float*)(ws + 35651584);              //     65,536 B
    float* Bx          = (float*)(ws + 35717120);              //  1,048,576 B
    float* cP          = (float*)(ws + 36765696);              //     32,768 B
    float* cH          = (float*)(ws + 36798464);              //     32,768 B
    unsigned short* bbf= (unsigned short*)(ws + 36831232);     //     32,768 B

    pre_kernel<<<17440, 256, 0, stream>>>((const float4*)x, (const float4*)Wd,
                                          (const float4*)B, (ushort4*)xb,
                                          (ushort4*)wb, (ushort4*)bbf, delta_raw);
    gemm_delta<<<256, 512, 0, stream>>>(xb, wb, bd, delta_raw);
    scan_bx<<<NB * NC, 128, 0, stream>>>(xb, bbf, delta_raw, A_log, Bx, cP, cH);
    y_kernel<<<NB * NC, 256, 0, stream>>>(xb, delta_raw, Bx, A_log, cP, cH, C, Dv, y);
}